// Round 6
// baseline (61.011 us; speedup 1.0000x reference)
//
#include <hip/hip_runtime.h>

// LIF membrane update, single fused kernel + tiny memset (split-K via
// device-scope atomics, NO fences):
//   v_new[b,n] = ALPHA*v[b,n] + sum_i x[b,i,n]*w[i,n] - V_TH*z[b,n]
//   z_new[b,n] = (v_new[b,n] - V_TH > 0) ? 1 : 0
// Shapes: x (128,1024,512) f32, w (1024,512) f32, v,z (128,512) f32.
// Memory-bound: x = 268 MB read once; floor ~41-43 us.
//
// R5: grid = 128 b x 2 slabs x 8 igroups = 2048 blocks (8/CU, 32 waves/CU).
// g = t&63 -> each wave-64 x-load is one contiguous 1KB segment; c = t>>6
// splits the 128-i group 4-way (32 i/thread). x loads non-temporal
// (stream-once; keep 2MB w L2-resident). Block LDS-reduces to 64 f4
// partials, atomicAdds them into ws acc (device-coherent at LLC -> no
// __threadfence, which R3 showed costs 13x via L2 writeback storms).
// __syncthreads() drains vmcnt, so the per-(b,slab) counter atomicAdd is
// ordered after the data atomics; the 8th arriver reads acc with
// agent-scope relaxed atomic loads (bypass stale local L2) and finishes
// the LIF update. ws acc+cnt zeroed by one 257KB memsetAsync per call.

typedef float f32x4 __attribute__((ext_vector_type(4)));

constexpr int B    = 128;
constexpr int N_IN = 1024;
constexpr int NN   = 512;
constexpr int NN4  = NN / 4;     // 128 float4 columns
constexpr int IG   = 8;          // igroups (split-K factor)
constexpr int IPG  = N_IN / IG;  // 128 i per group
constexpr int IPT  = IPG / 4;    // 32 i per thread
constexpr float ALPHA = 1.0f - 0.05f / 10.0f;  // 0.995
constexpr float V_TH  = 2.0f;

__global__ __launch_bounds__(256) void lif_stream(
    const f32x4* __restrict__ x4,
    const f32x4* __restrict__ w4,
    const f32x4* __restrict__ v4,
    const f32x4* __restrict__ z4,
    f32x4* __restrict__ vout4,
    f32x4* __restrict__ zout4,
    float* __restrict__ acc,       // [B*2][64*4] floats, zeroed per call
    unsigned* __restrict__ cnt)    // [B*2], zeroed per call
{
    const int t    = threadIdx.x;
    const int g    = t & 63;            // f4 column within slab (64 wide)
    const int c    = t >> 6;            // i-subchunk 0..3
    const unsigned bid = blockIdx.x;
    const int ig   = bid & 7;
    const int slab = (bid >> 3) & 1;
    const int b    = bid >> 4;

    const int col = slab * 64 + g;      // f4 column 0..127
    const int i0  = ig * IPG + c * IPT;

    const f32x4* __restrict__ xp = x4 + ((size_t)b * N_IN + i0) * NN4 + col;
    const f32x4* __restrict__ wp = w4 + (size_t)i0 * NN4 + col;

    f32x4 a = {0.f, 0.f, 0.f, 0.f};
    #pragma unroll 8
    for (int ii = 0; ii < IPT; ++ii) {
        f32x4 wv = wp[(size_t)ii * NN4];                               // L2-hit
        f32x4 xv = __builtin_nontemporal_load(&xp[(size_t)ii * NN4]);  // HBM stream
        a += xv * wv;
    }

    __shared__ f32x4 red[256];
    __shared__ bool lastblk;
    red[t] = a;
    __syncthreads();
    if (t < 128) red[t] += red[t + 128];
    __syncthreads();

    const size_t slot = ((size_t)(b * 2 + slab) * 64 + (t & 63)) * 4;
    if (t < 64) {
        f32x4 s = red[t] + red[t + 64];
        float* dst = acc + slot;
        atomicAdd(dst + 0, s.x);    // device-scope, coherent at LLC
        atomicAdd(dst + 1, s.y);
        atomicAdd(dst + 2, s.z);
        atomicAdd(dst + 3, s.w);
    }
    // __syncthreads emits s_waitcnt vmcnt(0) before the barrier -> all data
    // atomics have completed at the coherent point before t0's counter add.
    __syncthreads();
    if (t == 0)
        lastblk = (atomicAdd(&cnt[b * 2 + slab], 1u) == IG - 1);
    __syncthreads();
    if (!lastblk) return;

    if (t < 64) {
        const float* src = acc + slot;
        f32x4 s;
        s.x = __hip_atomic_load(src + 0, __ATOMIC_RELAXED, __HIP_MEMORY_SCOPE_AGENT);
        s.y = __hip_atomic_load(src + 1, __ATOMIC_RELAXED, __HIP_MEMORY_SCOPE_AGENT);
        s.z = __hip_atomic_load(src + 2, __ATOMIC_RELAXED, __HIP_MEMORY_SCOPE_AGENT);
        s.w = __hip_atomic_load(src + 3, __ATOMIC_RELAXED, __HIP_MEMORY_SCOPE_AGENT);
        const int idx = b * NN4 + slab * 64 + t;
        f32x4 vv = v4[idx];
        f32x4 zz = z4[idx];
        f32x4 vn = ALPHA * vv + s - V_TH * zz;
        vout4[idx] = vn;
        f32x4 zn;
        zn.x = (vn.x - V_TH > 0.f) ? 1.f : 0.f;
        zn.y = (vn.y - V_TH > 0.f) ? 1.f : 0.f;
        zn.z = (vn.z - V_TH > 0.f) ? 1.f : 0.f;
        zn.w = (vn.w - V_TH > 0.f) ? 1.f : 0.f;
        zout4[idx] = zn;
    }
}

extern "C" void kernel_launch(void* const* d_in, const int* in_sizes, int n_in,
                              void* d_out, int out_size, void* d_ws, size_t ws_size,
                              hipStream_t stream) {
    const f32x4* x = (const f32x4*)d_in[0];
    const f32x4* w = (const f32x4*)d_in[1];
    const f32x4* v = (const f32x4*)d_in[2];
    const f32x4* z = (const f32x4*)d_in[3];
    f32x4* vout = (f32x4*)d_out;                 // v_new: B*NN floats
    f32x4* zout = vout + (size_t)B * NN4;        // z_new follows flat

    unsigned* cnt = (unsigned*)d_ws;                       // B*2 = 1 KB
    float*    acc = (float*)((char*)d_ws + 1024);          // 256 KB

    hipMemsetAsync(d_ws, 0, 1024 + (size_t)B * 2 * 64 * 4 * sizeof(float),
                   stream);
    lif_stream<<<dim3(B * 2 * IG), dim3(256), 0, stream>>>(
        x, w, v, z, vout, zout, acc, cnt);
}

// Round 7
// 50.030 us; speedup vs baseline: 1.2195x; 1.2195x over previous
//
#include <hip/hip_runtime.h>

// LIF membrane update — ONE dispatch, full i-range per block, no cross-block
// reduction (fences/atomics/finalize all measured slower: R3=683us,
// R5=61us, R2 two-kernel=+4us overhead):
//   v_new[b,n] = ALPHA*v[b,n] + sum_i x[b,i,n]*w[i,n] - V_TH*z[b,n]
//   z_new[b,n] = (v_new[b,n] - V_TH > 0) ? 1 : 0
// Shapes: x (128,1024,512) f32, w (1024,512) f32, v,z (128,512) f32.
// Memory-bound: 259 MB mandatory traffic; floor ~41 us @ 6.3 TB/s.
//
// R6: block = 1024 thr = (1 batch x 64 f4-cols x all 1024 i).
//   g = t&63  -> wave-64 load = one contiguous 1KB segment (best TA path)
//   c = t>>6  -> 16-way i-split, 64 i per thread
// Grid = 128 b x 2 slabs = 256 blocks = exactly 1 block/CU (no tail),
// 16 waves/CU (= R0/R2 occupancy, proven sufficient for ~5.5+ TB/s).
// x loads non-temporal (stream-once); w regular loads (2MB, L2-resident).
// 4-stage LDS tree reduce, t<64 applies LIF + threshold in-block.

typedef float f32x4 __attribute__((ext_vector_type(4)));

constexpr int B    = 128;
constexpr int N_IN = 1024;
constexpr int NN   = 512;
constexpr int NN4  = NN / 4;      // 128 f4 columns per i-row
constexpr int IPT  = N_IN / 16;   // 64 i per thread (16 chunks)
constexpr float ALPHA = 1.0f - 0.05f / 10.0f;  // 0.995
constexpr float V_TH  = 2.0f;

__global__ __launch_bounds__(1024) void lif_fused(
    const f32x4* __restrict__ x4,
    const f32x4* __restrict__ w4,
    const f32x4* __restrict__ v4,
    const f32x4* __restrict__ z4,
    f32x4* __restrict__ vout4,
    f32x4* __restrict__ zout4)
{
    const int t    = threadIdx.x;
    const int g    = t & 63;           // f4 column within slab (64 wide)
    const int c    = t >> 6;           // i-chunk 0..15
    const int slab = blockIdx.x & 1;   // 0..1 (halves of the 128 f4 cols)
    const int b    = blockIdx.x >> 1;  // 0..127

    const int col = slab * 64 + g;     // f4 column 0..127
    const int i0  = c * IPT;

    const f32x4* __restrict__ xp = x4 + ((size_t)b * N_IN + i0) * NN4 + col;
    const f32x4* __restrict__ wp = w4 + (size_t)i0 * NN4 + col;

    f32x4 a = {0.f, 0.f, 0.f, 0.f};
    #pragma unroll 8
    for (int ii = 0; ii < IPT; ++ii) {
        f32x4 wv = wp[(size_t)ii * NN4];                               // L2-hit
        f32x4 xv = __builtin_nontemporal_load(&xp[(size_t)ii * NN4]);  // HBM stream
        a += xv * wv;
    }

    __shared__ f32x4 red[1024];        // 16 KB
    red[t] = a;
    __syncthreads();
    if (t < 512) red[t] += red[t + 512];
    __syncthreads();
    if (t < 256) red[t] += red[t + 256];
    __syncthreads();
    if (t < 128) red[t] += red[t + 128];
    __syncthreads();

    if (t < 64) {
        f32x4 s = red[t] + red[t + 64];
        const int idx = b * NN4 + slab * 64 + t;
        f32x4 vv = v4[idx];
        f32x4 zz = z4[idx];
        f32x4 vn = ALPHA * vv + s - V_TH * zz;
        vout4[idx] = vn;
        f32x4 zn;
        zn.x = (vn.x - V_TH > 0.f) ? 1.f : 0.f;
        zn.y = (vn.y - V_TH > 0.f) ? 1.f : 0.f;
        zn.z = (vn.z - V_TH > 0.f) ? 1.f : 0.f;
        zn.w = (vn.w - V_TH > 0.f) ? 1.f : 0.f;
        zout4[idx] = zn;
    }
}

extern "C" void kernel_launch(void* const* d_in, const int* in_sizes, int n_in,
                              void* d_out, int out_size, void* d_ws, size_t ws_size,
                              hipStream_t stream) {
    const f32x4* x = (const f32x4*)d_in[0];
    const f32x4* w = (const f32x4*)d_in[1];
    const f32x4* v = (const f32x4*)d_in[2];
    const f32x4* z = (const f32x4*)d_in[3];
    f32x4* vout = (f32x4*)d_out;                 // v_new: B*NN floats
    f32x4* zout = vout + (size_t)B * NN4;        // z_new follows flat

    lif_fused<<<dim3(B * 2), dim3(1024), 0, stream>>>(x, w, v, z, vout, zout);
}